// Round 2
// baseline (7644.570 us; speedup 1.0000x reference)
//
#include <hip/hip_runtime.h>
#include <stdint.h>

#define H_DIM   1024
#define G3      3072
#define EMB     50
#define TSTEPS  100
#define NB      4096
#define NLABEL  15

typedef __bf16 bf16x8 __attribute__((ext_vector_type(8)));
typedef float  f32x4  __attribute__((ext_vector_type(4)));

__device__ inline uint16_t f2bf(float f) {
  uint32_t u = __builtin_bit_cast(uint32_t, f);
  u += 0x7FFFu + ((u >> 16) & 1u);   // round-to-nearest-even
  return (uint16_t)(u >> 16);
}

__device__ inline void gld16(const void* g, void* l) {
  __builtin_amdgcn_global_load_lds(
      (const __attribute__((address_space(1))) uint32_t*)g,
      (__attribute__((address_space(3))) uint32_t*)l, 16, 0, 0);
}

// ---------------- prep kernels (unchanged; buffers stay LINEAR) ----------------

// rec_kernel [1024][3072] f32  ->  recT [3072][1024] bf16 (B^T layout)
__global__ __launch_bounds__(256) void prep_recT(const float* __restrict__ rec,
                                                 uint16_t* __restrict__ recT) {
  __shared__ uint16_t st[64][72];
  const int n0 = blockIdx.x * 64;   // over 3072
  const int k0 = blockIdx.y * 64;   // over 1024
  const int tid = threadIdx.x;
#pragma unroll
  for (int i = 0; i < 16; ++i) {
    int idx = tid + i * 256;
    int r = idx >> 6;    // k offset
    int c = idx & 63;    // n offset
    st[c][r] = f2bf(rec[(size_t)(k0 + r) * G3 + n0 + c]);
  }
  __syncthreads();
#pragma unroll
  for (int i = 0; i < 16; ++i) {
    int idx = tid + i * 256;
    int r = idx >> 6;    // n offset
    int c = idx & 63;    // k offset
    recT[(size_t)(n0 + r) * H_DIM + k0 + c] = st[r][c];
  }
}

// kernel [50][3072] f32 -> kerT [3072][64] bf16, zero-padded k in [50,64)
__global__ __launch_bounds__(256) void prep_kerT(const float* __restrict__ ker,
                                                 uint16_t* __restrict__ kerT) {
  int n = blockIdx.x * 4 + (threadIdx.x >> 6);   // 0..3071
  int k = threadIdx.x & 63;
  float v = (k < EMB) ? ker[(size_t)k * G3 + n] : 0.f;
  kerT[(size_t)n * 64 + k] = f2bf(v);
}

// embt [100][4096][64] bf16 = emb_table[x[b,t]], zero-padded cols [50,64)
__global__ __launch_bounds__(256) void prep_embt(const int* __restrict__ x,
                                                 const float* __restrict__ tab,
                                                 uint16_t* __restrict__ embt) {
  int g = blockIdx.x * 4 + (threadIdx.x >> 6);   // t*4096 + b
  int t = g >> 12;
  int b = g & 4095;
  int k = threadIdx.x & 63;
  int idx = x[b * TSTEPS + t];
  float v = (k < EMB) ? tab[(size_t)idx * EMB + k] : 0.f;
  embt[(size_t)g * 64 + k] = f2bf(v);
}

// ---------------- fused GRU step ----------------
// grid (32,16), block 256. Tile: 128 batch rows x 64 hidden cols, all 3 gates.
// 2-phase double-buffered pipeline, XOR-swizzled LDS (pre-swizzled global src,
// linear global_load_lds dest, swizzled ds_read — both-sides involution).
__global__ __launch_bounds__(256) void gru_step_kernel(
    const uint16_t* __restrict__ hb_prev,   // [4096][1024] bf16
    float* __restrict__ hf,                 // [4096][1024] f32 (in-place)
    uint16_t* __restrict__ hb_next,         // [4096][1024] bf16
    const uint16_t* __restrict__ recT,      // [3072][1024] bf16
    const uint16_t* __restrict__ kerT,      // [3072][64]   bf16
    const uint16_t* __restrict__ embt,      // [4096][64]   bf16 (this step)
    const float* __restrict__ bias_i,       // [3072]
    const float* __restrict__ bias_r) {     // [3072]
  __shared__ __align__(16) uint16_t sA[2][128 * 64];
  __shared__ __align__(16) uint16_t sB[2][3][64 * 64];

  const int tid  = threadIdx.x;
  const int lane = tid & 63;
  const int wid  = tid >> 6;
  const int wm   = wid >> 1;   // wave row 0..1
  const int wn   = wid & 1;    // wave col 0..1
  const int r0   = blockIdx.x * 128;
  const int j0   = blockIdx.y * 64;

  // swizzle: stored_elem = row*64 + (e ^ ((row&7)<<3)); staged chunk q covers
  // rows q*8+(lane>>3), so row&7 == lane>>3 -> source col starts at:
  const int swz8 = 8 * ((lane & 7) ^ (lane >> 3));

  f32x4 accZ[4][2], accR[4][2], accH[4][2], accX[4][2];
#pragma unroll
  for (int m = 0; m < 4; ++m)
#pragma unroll
    for (int n = 0; n < 2; ++n) {
      accZ[m][n] = (f32x4){0.f, 0.f, 0.f, 0.f};
      accR[m][n] = (f32x4){0.f, 0.f, 0.f, 0.f};
      accH[m][n] = (f32x4){0.f, 0.f, 0.f, 0.f};
      accX[m][n] = (f32x4){0.f, 0.f, 0.f, 0.f};
    }

  // STAGE tile kt (0..15 recurrent, 16 = input projection) into buffer buf.
  auto STAGE = [&](int buf, int kt) {
    if (kt < 16) {
      const int k0 = kt * 64;
#pragma unroll
      for (int i = 0; i < 4; ++i) {          // A tile 128x64 = 16 KB
        int q   = wid * 4 + i;
        int row = q * 8 + (lane >> 3);
        gld16(hb_prev + (size_t)(r0 + row) * H_DIM + k0 + swz8,
              &sA[buf][q * 512 + lane * 8]);
      }
#pragma unroll
      for (int i = 0; i < 6; ++i) {          // 3 B panels, 8 KB each
        int c = wid * 6 + i;
        int g = c >> 3, q = c & 7;
        int n = q * 8 + (lane >> 3);
        gld16(recT + (size_t)(g * H_DIM + j0 + n) * H_DIM + k0 + swz8,
              &sB[buf][g][q * 512 + lane * 8]);
      }
    } else {
#pragma unroll
      for (int i = 0; i < 4; ++i) {
        int q   = wid * 4 + i;
        int row = q * 8 + (lane >> 3);
        gld16(embt + (size_t)(r0 + row) * 64 + swz8,
              &sA[buf][q * 512 + lane * 8]);
      }
#pragma unroll
      for (int i = 0; i < 6; ++i) {
        int c = wid * 6 + i;
        int g = c >> 3, q = c & 7;
        int n = q * 8 + (lane >> 3);
        gld16(kerT + (size_t)(g * H_DIM + j0 + n) * 64 + swz8,
              &sB[buf][g][q * 512 + lane * 8]);
      }
    }
  };

  // COMPUTE buffer buf; gate-2 MFMA accumulates into accG2 (accH or accX),
  // statically bound at each (inlined) call site.
  auto COMPUTE = [&](int buf, f32x4 (&accG2)[4][2]) {
#pragma unroll
    for (int ks = 0; ks < 2; ++ks) {
      const int colswz = (ks * 32 + (lane >> 4) * 8) ^ ((lane & 7) << 3);
      bf16x8 af[4];
#pragma unroll
      for (int mf = 0; mf < 4; ++mf)
        af[mf] = *reinterpret_cast<const bf16x8*>(
            &sA[buf][(wm * 64 + mf * 16 + (lane & 15)) * 64 + colswz]);
#pragma unroll
      for (int nf = 0; nf < 2; ++nf) {
        int nn = wn * 32 + nf * 16 + (lane & 15);
        int bo = nn * 64 + colswz;
        bf16x8 bz = *reinterpret_cast<const bf16x8*>(&sB[buf][0][bo]);
        bf16x8 br = *reinterpret_cast<const bf16x8*>(&sB[buf][1][bo]);
        bf16x8 bh = *reinterpret_cast<const bf16x8*>(&sB[buf][2][bo]);
#pragma unroll
        for (int mf = 0; mf < 4; ++mf) {
          accZ[mf][nf]  = __builtin_amdgcn_mfma_f32_16x16x32_bf16(af[mf], bz, accZ[mf][nf], 0, 0, 0);
          accR[mf][nf]  = __builtin_amdgcn_mfma_f32_16x16x32_bf16(af[mf], br, accR[mf][nf], 0, 0, 0);
          accG2[mf][nf] = __builtin_amdgcn_mfma_f32_16x16x32_bf16(af[mf], bh, accG2[mf][nf], 0, 0, 0);
        }
      }
    }
  };

  // -------- 2-phase pipeline over 17 tiles (16 recurrent + input proj) ------
  STAGE(0, 0);
  __syncthreads();                       // vmcnt(0) drain + barrier
  for (int kt = 0; kt < 16; ++kt) {
    const int cur = kt & 1;
    STAGE(cur ^ 1, kt + 1);              // issue next tile's loads FIRST
    COMPUTE(cur, accH);                  // ds_read + MFMA cover the latency
    __syncthreads();                     // one drain+barrier per tile
  }
  COMPUTE(0, accX);                      // tile 16 sits in buffer 0

  // -------- epilogue: gates in fp32, write h (f32 master + bf16) --------
#pragma unroll
  for (int nf = 0; nf < 2; ++nf) {
    int col = j0 + wn * 32 + nf * 16 + (lane & 15);
    float b_z = bias_i[col] + bias_r[col];
    float b_r = bias_i[H_DIM + col] + bias_r[H_DIM + col];
    float bih = bias_i[2 * H_DIM + col];
    float brh = bias_r[2 * H_DIM + col];
#pragma unroll
    for (int mf = 0; mf < 4; ++mf) {
#pragma unroll
      for (int q = 0; q < 4; ++q) {
        int row = r0 + wm * 64 + mf * 16 + (lane >> 4) * 4 + q;
        float z  = 1.f / (1.f + __expf(-(accZ[mf][nf][q] + b_z)));
        float rr = 1.f / (1.f + __expf(-(accR[mf][nf][q] + b_r)));
        float pre = accX[mf][nf][q] + bih + rr * (accH[mf][nf][q] + brh);
        float hc  = 2.f / (1.f + __expf(-2.f * pre)) - 1.f;   // tanh
        size_t idx = (size_t)row * H_DIM + col;
        float hold = hf[idx];
        float hnew = z * hold + (1.f - z) * hc;
        hf[idx] = hnew;
        hb_next[idx] = f2bf(hnew);
      }
    }
  }
}

// ---------------- final logits ----------------
__global__ __launch_bounds__(64) void logits_kernel(const float* __restrict__ hf,
                                                    const float* __restrict__ Wd,
                                                    const float* __restrict__ bd,
                                                    float* __restrict__ out) {
  int b = blockIdx.x;
  int l = threadIdx.x;
  float p[NLABEL];
#pragma unroll
  for (int o = 0; o < NLABEL; ++o) p[o] = 0.f;
  for (int kb = 0; kb < 16; ++kb) {
    int k = kb * 64 + l;
    float hv = hf[(size_t)b * H_DIM + k];
#pragma unroll
    for (int o = 0; o < NLABEL; ++o) p[o] += hv * Wd[k * NLABEL + o];
  }
#pragma unroll
  for (int o = 0; o < NLABEL; ++o) {
#pragma unroll
    for (int s = 32; s; s >>= 1) p[o] += __shfl_xor(p[o], s);
  }
  if (l == 0) {
#pragma unroll
    for (int o = 0; o < NLABEL; ++o) out[(size_t)b * NLABEL + o] = p[o] + bd[o];
  }
}

// ---------------- launch ----------------
extern "C" void kernel_launch(void* const* d_in, const int* in_sizes, int n_in,
                              void* d_out, int out_size, void* d_ws, size_t ws_size,
                              hipStream_t stream) {
  const int*   x          = (const int*)d_in[0];
  // d_in[1] = drop_rate (static 0, ignored)
  const float* emb_table  = (const float*)d_in[2];
  const float* kernel_w   = (const float*)d_in[3];
  const float* rec_kernel = (const float*)d_in[4];
  const float* bias_i     = (const float*)d_in[5];
  const float* bias_r     = (const float*)d_in[6];
  const float* Wd         = (const float*)d_in[7];
  const float* bd         = (const float*)d_in[8];
  float* out = (float*)d_out;

  char* ws = (char*)d_ws;
  size_t off = 0;
  auto alloc = [&](size_t bytes) {
    char* p = ws + off;
    off += (bytes + 255) & ~(size_t)255;
    return p;
  };
  float*    hf   = (float*)alloc((size_t)NB * H_DIM * 4);
  uint16_t* hb0  = (uint16_t*)alloc((size_t)NB * H_DIM * 2);
  uint16_t* hb1  = (uint16_t*)alloc((size_t)NB * H_DIM * 2);
  uint16_t* recT = (uint16_t*)alloc((size_t)G3 * H_DIM * 2);
  uint16_t* kerT = (uint16_t*)alloc((size_t)G3 * 64 * 2);
  uint16_t* embt = (uint16_t*)alloc((size_t)TSTEPS * NB * 64 * 2);
  if (off > ws_size) return;  // insufficient workspace -> fail loudly

  hipMemsetAsync(hf, 0, (size_t)NB * H_DIM * 4, stream);
  hipMemsetAsync(hb0, 0, (size_t)NB * H_DIM * 2, stream);

  prep_recT<<<dim3(G3 / 64, H_DIM / 64), 256, 0, stream>>>(rec_kernel, recT);
  prep_kerT<<<G3 / 4, 256, 0, stream>>>(kernel_w, kerT);
  prep_embt<<<TSTEPS * NB / 4, 256, 0, stream>>>(x, emb_table, embt);

  uint16_t* hb[2] = {hb0, hb1};
  for (int t = 0; t < TSTEPS; ++t) {
    gru_step_kernel<<<dim3(NB / 128, H_DIM / 64), 256, 0, stream>>>(
        hb[t & 1], hf, hb[(t + 1) & 1], recT, kerT,
        embt + (size_t)t * NB * 64, bias_i, bias_r);
  }
  logits_kernel<<<NB, 64, 0, stream>>>(hf, Wd, bd, out);
}

// Round 3
// 3932.159 us; speedup vs baseline: 1.9441x; 1.9441x over previous
//
#include <hip/hip_runtime.h>
#include <stdint.h>

#define H_DIM   1024
#define G3      3072
#define EMB     50
#define TSTEPS  100
#define NB      4096
#define NLABEL  15

typedef __bf16 bf16x8 __attribute__((ext_vector_type(8)));
typedef float  f32x4  __attribute__((ext_vector_type(4)));

__device__ inline uint16_t f2bf(float f) {
  uint32_t u = __builtin_bit_cast(uint32_t, f);
  u += 0x7FFFu + ((u >> 16) & 1u);   // round-to-nearest-even
  return (uint16_t)(u >> 16);
}

__device__ inline void gld16(const void* g, void* l) {
  __builtin_amdgcn_global_load_lds(
      (const __attribute__((address_space(1))) uint32_t*)g,
      (__attribute__((address_space(3))) uint32_t*)l, 16, 0, 0);
}

// ---------------- prep kernels (buffers stay LINEAR) ----------------

// rec_kernel [1024][3072] f32  ->  recT [3072][1024] bf16 (B^T layout)
__global__ __launch_bounds__(256) void prep_recT(const float* __restrict__ rec,
                                                 uint16_t* __restrict__ recT) {
  __shared__ uint16_t st[64][72];
  const int n0 = blockIdx.x * 64;   // over 3072
  const int k0 = blockIdx.y * 64;   // over 1024
  const int tid = threadIdx.x;
#pragma unroll
  for (int i = 0; i < 16; ++i) {
    int idx = tid + i * 256;
    int r = idx >> 6;    // k offset
    int c = idx & 63;    // n offset
    st[c][r] = f2bf(rec[(size_t)(k0 + r) * G3 + n0 + c]);
  }
  __syncthreads();
#pragma unroll
  for (int i = 0; i < 16; ++i) {
    int idx = tid + i * 256;
    int r = idx >> 6;    // n offset
    int c = idx & 63;    // k offset
    recT[(size_t)(n0 + r) * H_DIM + k0 + c] = st[r][c];
  }
}

// kernel [50][3072] f32 -> kerT [3072][64] bf16, zero-padded k in [50,64)
__global__ __launch_bounds__(256) void prep_kerT(const float* __restrict__ ker,
                                                 uint16_t* __restrict__ kerT) {
  int n = blockIdx.x * 4 + (threadIdx.x >> 6);   // 0..3071
  int k = threadIdx.x & 63;
  float v = (k < EMB) ? ker[(size_t)k * G3 + n] : 0.f;
  kerT[(size_t)n * 64 + k] = f2bf(v);
}

// embt [100][4096][64] bf16 = emb_table[x[b,t]], zero-padded cols [50,64)
__global__ __launch_bounds__(256) void prep_embt(const int* __restrict__ x,
                                                 const float* __restrict__ tab,
                                                 uint16_t* __restrict__ embt) {
  int g = blockIdx.x * 4 + (threadIdx.x >> 6);   // t*4096 + b
  int t = g >> 12;
  int b = g & 4095;
  int k = threadIdx.x & 63;
  int idx = x[b * TSTEPS + t];
  float v = (k < EMB) ? tab[(size_t)idx * EMB + k] : 0.f;
  embt[(size_t)g * 64 + k] = f2bf(v);
}

// ---------------- fused GRU step ----------------
// grid 256 linear (1 block/CU), block 512 (8 waves, 2x4 wave grid).
// Tile: 128 batch rows x 128 hidden cols, all 3 gates. Counted-vmcnt
// double-buffered pipeline (vmcnt(8), never 0 in main loop), raw s_barrier.
// XOR-swizzled LDS via pre-swizzled global src + swizzled ds_read.
// col-block = bid&7 -> pins each 786KB recT column slice to one XCD's L2.
__global__ __launch_bounds__(512, 2) void gru_step_kernel(
    const uint16_t* __restrict__ hb_prev,   // [4096][1024] bf16
    float* __restrict__ hf,                 // [4096][1024] f32 (in-place)
    uint16_t* __restrict__ hb_next,         // [4096][1024] bf16
    const uint16_t* __restrict__ recT,      // [3072][1024] bf16
    const uint16_t* __restrict__ kerT,      // [3072][64]   bf16
    const uint16_t* __restrict__ embt,      // [4096][64]   bf16 (this step)
    const float* __restrict__ bias_i,       // [3072]
    const float* __restrict__ bias_r) {     // [3072]
  __shared__ __align__(16) uint16_t sA[2][128 * 64];      // 32 KB
  __shared__ __align__(16) uint16_t sB[2][3][128 * 64];   // 96 KB

  const int tid  = threadIdx.x;
  const int lane = tid & 63;
  const int wid  = tid >> 6;     // 0..7
  const int wm   = wid >> 2;     // wave row 0..1  (64 rows each)
  const int wn   = wid & 3;      // wave col 0..3  (32 cols each)
  const int bid  = blockIdx.x;
  const int r0   = (bid >> 3) * 128;   // 32 row-blocks
  const int j0   = (bid & 7) * 128;    // 8 col-blocks -> XCD-pinned

  // staged chunk covers row with row&7 == lane>>3 -> swizzled source col:
  const int swz8 = 8 * ((lane & 7) ^ (lane >> 3));

  f32x4 accZ[4][2], accR[4][2], accH[4][2], accX[4][2];
#pragma unroll
  for (int m = 0; m < 4; ++m)
#pragma unroll
    for (int n = 0; n < 2; ++n) {
      accZ[m][n] = (f32x4){0.f, 0.f, 0.f, 0.f};
      accR[m][n] = (f32x4){0.f, 0.f, 0.f, 0.f};
      accH[m][n] = (f32x4){0.f, 0.f, 0.f, 0.f};
      accX[m][n] = (f32x4){0.f, 0.f, 0.f, 0.f};
    }

  // STAGE tile kt (0..15 recurrent, 16 = input projection): 8 gld16/thread.
  auto STAGE = [&](int buf, int kt) {
    if (kt < 16) {
      const int k0 = kt * 64;
#pragma unroll
      for (int i = 0; i < 2; ++i) {          // A: 128x64 = 16 KB
        int row = wid * 16 + i * 8 + (lane >> 3);
        gld16(hb_prev + (size_t)(r0 + row) * H_DIM + k0 + swz8,
              &sA[buf][(wid * 128 + i * 64 + lane) * 8]);
      }
#pragma unroll
      for (int i = 0; i < 6; ++i) {          // B: 3 panels x 128x64 = 48 KB
        int cb = wid * 6 + i;                // 0..47
        int g  = cb >> 4;
        int n  = (cb & 15) * 8 + (lane >> 3);
        gld16(recT + (size_t)(g * H_DIM + j0 + n) * H_DIM + k0 + swz8,
              &sB[buf][g][((cb & 15) * 64 + lane) * 8]);
      }
    } else {
#pragma unroll
      for (int i = 0; i < 2; ++i) {
        int row = wid * 16 + i * 8 + (lane >> 3);
        gld16(embt + (size_t)(r0 + row) * 64 + swz8,
              &sA[buf][(wid * 128 + i * 64 + lane) * 8]);
      }
#pragma unroll
      for (int i = 0; i < 6; ++i) {
        int cb = wid * 6 + i;
        int g  = cb >> 4;
        int n  = (cb & 15) * 8 + (lane >> 3);
        gld16(kerT + (size_t)(g * H_DIM + j0 + n) * 64 + swz8,
              &sB[buf][g][((cb & 15) * 64 + lane) * 8]);
      }
    }
  };

  // COMPUTE buffer buf; gate-2 accumulates into accG2 (accH or accX).
  auto COMPUTE = [&](int buf, f32x4 (&accG2)[4][2]) {
#pragma unroll
    for (int ks = 0; ks < 2; ++ks) {
      const int colswz = (ks * 32 + (lane >> 4) * 8) ^ ((lane & 7) << 3);
      bf16x8 af[4];
#pragma unroll
      for (int mf = 0; mf < 4; ++mf)
        af[mf] = *reinterpret_cast<const bf16x8*>(
            &sA[buf][(wm * 64 + mf * 16 + (lane & 15)) * 64 + colswz]);
#pragma unroll
      for (int nf = 0; nf < 2; ++nf) {
        int nn = wn * 32 + nf * 16 + (lane & 15);   // 0..127
        int bo = nn * 64 + colswz;
        bf16x8 bz = *reinterpret_cast<const bf16x8*>(&sB[buf][0][bo]);
        bf16x8 br = *reinterpret_cast<const bf16x8*>(&sB[buf][1][bo]);
        bf16x8 bh = *reinterpret_cast<const bf16x8*>(&sB[buf][2][bo]);
#pragma unroll
        for (int mf = 0; mf < 4; ++mf) {
          accZ[mf][nf]  = __builtin_amdgcn_mfma_f32_16x16x32_bf16(af[mf], bz, accZ[mf][nf], 0, 0, 0);
          accR[mf][nf]  = __builtin_amdgcn_mfma_f32_16x16x32_bf16(af[mf], br, accR[mf][nf], 0, 0, 0);
          accG2[mf][nf] = __builtin_amdgcn_mfma_f32_16x16x32_bf16(af[mf], bh, accG2[mf][nf], 0, 0, 0);
        }
      }
    }
  };

  // -------- counted-vmcnt pipeline over 17 tiles --------
  STAGE(0, 0);
  for (int t = 0; t < 16; ++t) {
    const int cur = t & 1;
    STAGE(cur ^ 1, t + 1);                       // 8 more loads in flight
    asm volatile("s_waitcnt vmcnt(8)" ::: "memory");   // cur tile landed
    __builtin_amdgcn_s_barrier();                // everyone's cur landed
    COMPUTE(cur, accH);
    asm volatile("s_waitcnt lgkmcnt(0)" ::: "memory"); // reads done
    __builtin_amdgcn_s_barrier();                // safe to overwrite cur
  }
  asm volatile("s_waitcnt vmcnt(0)" ::: "memory");     // tile 16 landed
  __builtin_amdgcn_s_barrier();
  COMPUTE(0, accX);                              // tile 16 sits in buffer 0

  // -------- epilogue: gates in fp32, write h (f32 master + bf16) --------
#pragma unroll
  for (int nf = 0; nf < 2; ++nf) {
    int col = j0 + wn * 32 + nf * 16 + (lane & 15);
    float b_z = bias_i[col] + bias_r[col];
    float b_r = bias_i[H_DIM + col] + bias_r[H_DIM + col];
    float bih = bias_i[2 * H_DIM + col];
    float brh = bias_r[2 * H_DIM + col];
#pragma unroll
    for (int mf = 0; mf < 4; ++mf) {
#pragma unroll
      for (int q = 0; q < 4; ++q) {
        int row = r0 + wm * 64 + mf * 16 + (lane >> 4) * 4 + q;
        float z  = 1.f / (1.f + __expf(-(accZ[mf][nf][q] + b_z)));
        float rr = 1.f / (1.f + __expf(-(accR[mf][nf][q] + b_r)));
        float pre = accX[mf][nf][q] + bih + rr * (accH[mf][nf][q] + brh);
        float hc  = 2.f / (1.f + __expf(-2.f * pre)) - 1.f;   // tanh
        size_t idx = (size_t)row * H_DIM + col;
        float hold = hf[idx];
        float hnew = z * hold + (1.f - z) * hc;
        hf[idx] = hnew;
        hb_next[idx] = f2bf(hnew);
      }
    }
  }
}

// ---------------- final logits ----------------
__global__ __launch_bounds__(64) void logits_kernel(const float* __restrict__ hf,
                                                    const float* __restrict__ Wd,
                                                    const float* __restrict__ bd,
                                                    float* __restrict__ out) {
  int b = blockIdx.x;
  int l = threadIdx.x;
  float p[NLABEL];
#pragma unroll
  for (int o = 0; o < NLABEL; ++o) p[o] = 0.f;
  for (int kb = 0; kb < 16; ++kb) {
    int k = kb * 64 + l;
    float hv = hf[(size_t)b * H_DIM + k];
#pragma unroll
    for (int o = 0; o < NLABEL; ++o) p[o] += hv * Wd[k * NLABEL + o];
  }
#pragma unroll
  for (int o = 0; o < NLABEL; ++o) {
#pragma unroll
    for (int s = 32; s; s >>= 1) p[o] += __shfl_xor(p[o], s);
  }
  if (l == 0) {
#pragma unroll
    for (int o = 0; o < NLABEL; ++o) out[(size_t)b * NLABEL + o] = p[o] + bd[o];
  }
}

// ---------------- launch ----------------
extern "C" void kernel_launch(void* const* d_in, const int* in_sizes, int n_in,
                              void* d_out, int out_size, void* d_ws, size_t ws_size,
                              hipStream_t stream) {
  const int*   x          = (const int*)d_in[0];
  // d_in[1] = drop_rate (static 0, ignored)
  const float* emb_table  = (const float*)d_in[2];
  const float* kernel_w   = (const float*)d_in[3];
  const float* rec_kernel = (const float*)d_in[4];
  const float* bias_i     = (const float*)d_in[5];
  const float* bias_r     = (const float*)d_in[6];
  const float* Wd         = (const float*)d_in[7];
  const float* bd         = (const float*)d_in[8];
  float* out = (float*)d_out;

  char* ws = (char*)d_ws;
  size_t off = 0;
  auto alloc = [&](size_t bytes) {
    char* p = ws + off;
    off += (bytes + 255) & ~(size_t)255;
    return p;
  };
  float*    hf   = (float*)alloc((size_t)NB * H_DIM * 4);
  uint16_t* hb0  = (uint16_t*)alloc((size_t)NB * H_DIM * 2);
  uint16_t* hb1  = (uint16_t*)alloc((size_t)NB * H_DIM * 2);
  uint16_t* recT = (uint16_t*)alloc((size_t)G3 * H_DIM * 2);
  uint16_t* kerT = (uint16_t*)alloc((size_t)G3 * 64 * 2);
  uint16_t* embt = (uint16_t*)alloc((size_t)TSTEPS * NB * 64 * 2);
  if (off > ws_size) return;  // insufficient workspace -> fail loudly

  hipMemsetAsync(hf, 0, (size_t)NB * H_DIM * 4, stream);
  hipMemsetAsync(hb0, 0, (size_t)NB * H_DIM * 2, stream);

  prep_recT<<<dim3(G3 / 64, H_DIM / 64), 256, 0, stream>>>(rec_kernel, recT);
  prep_kerT<<<G3 / 4, 256, 0, stream>>>(kernel_w, kerT);
  prep_embt<<<TSTEPS * NB / 4, 256, 0, stream>>>(x, emb_table, embt);

  uint16_t* hb[2] = {hb0, hb1};
  for (int t = 0; t < TSTEPS; ++t) {
    gru_step_kernel<<<256, 512, 0, stream>>>(
        hb[t & 1], hf, hb[(t + 1) & 1], recT, kerT,
        embt + (size_t)t * NB * 64, bias_i, bias_r);
  }
  logits_kernel<<<NB, 64, 0, stream>>>(hf, Wd, bd, out);
}

// Round 4
// 3543.841 us; speedup vs baseline: 2.1571x; 1.1096x over previous
//
#include <hip/hip_runtime.h>
#include <stdint.h>

#define H_DIM   1024
#define G3      3072
#define EMB     50
#define TSTEPS  100
#define NB      4096
#define NLABEL  15

typedef __bf16 bf16x8 __attribute__((ext_vector_type(8)));
typedef float  f32x4  __attribute__((ext_vector_type(4)));

__device__ inline uint16_t f2bf(float f) {
  uint32_t u = __builtin_bit_cast(uint32_t, f);
  u += 0x7FFFu + ((u >> 16) & 1u);   // round-to-nearest-even
  return (uint16_t)(u >> 16);
}

__device__ inline void gld16(const void* g, void* l) {
  __builtin_amdgcn_global_load_lds(
      (const __attribute__((address_space(1))) uint32_t*)g,
      (__attribute__((address_space(3))) uint32_t*)l, 16, 0, 0);
}

#define VM_WAIT(n) asm volatile("s_waitcnt vmcnt(" #n ")" ::: "memory")
#define LGKM0()    do { asm volatile("s_waitcnt lgkmcnt(0)" ::: "memory"); \
                        __builtin_amdgcn_sched_barrier(0); } while (0)
#define BAR()      __builtin_amdgcn_s_barrier()

// ---------------- prep kernels (buffers stay LINEAR) ----------------

// rec_kernel [1024][3072] f32  ->  recT [3072][1024] bf16 (B^T layout)
__global__ __launch_bounds__(256) void prep_recT(const float* __restrict__ rec,
                                                 uint16_t* __restrict__ recT) {
  __shared__ uint16_t st[64][72];
  const int n0 = blockIdx.x * 64;   // over 3072
  const int k0 = blockIdx.y * 64;   // over 1024
  const int tid = threadIdx.x;
#pragma unroll
  for (int i = 0; i < 16; ++i) {
    int idx = tid + i * 256;
    int r = idx >> 6;    // k offset
    int c = idx & 63;    // n offset
    st[c][r] = f2bf(rec[(size_t)(k0 + r) * G3 + n0 + c]);
  }
  __syncthreads();
#pragma unroll
  for (int i = 0; i < 16; ++i) {
    int idx = tid + i * 256;
    int r = idx >> 6;    // n offset
    int c = idx & 63;    // k offset
    recT[(size_t)(n0 + r) * H_DIM + k0 + c] = st[r][c];
  }
}

// kernel [50][3072] f32 -> kerT [3072][64] bf16, zero-padded k in [50,64)
__global__ __launch_bounds__(256) void prep_kerT(const float* __restrict__ ker,
                                                 uint16_t* __restrict__ kerT) {
  int n = blockIdx.x * 4 + (threadIdx.x >> 6);   // 0..3071
  int k = threadIdx.x & 63;
  float v = (k < EMB) ? ker[(size_t)k * G3 + n] : 0.f;
  kerT[(size_t)n * 64 + k] = f2bf(v);
}

// embt [100][4096][64] bf16 = emb_table[x[b,t]], zero-padded cols [50,64)
// One thread handles a (row, col-pair): float2 read, packed 2xbf16 write.
__global__ __launch_bounds__(256) void prep_embt(const int* __restrict__ x,
                                                 const float* __restrict__ tab,
                                                 uint16_t* __restrict__ embt) {
  int idx = blockIdx.x * 256 + threadIdx.x;   // pair index
  int g = idx >> 5;          // row: t*4096 + b
  int p = idx & 31;          // pair 0..31 -> cols 2p, 2p+1
  int t = g >> 12;
  int b = g & 4095;
  int row = x[b * TSTEPS + t];
  float2 v;
  if (p < 25) v = *reinterpret_cast<const float2*>(tab + (size_t)row * EMB + 2 * p);
  else { v.x = 0.f; v.y = 0.f; }
  uint32_t packed = (uint32_t)f2bf(v.x) | ((uint32_t)f2bf(v.y) << 16);
  *reinterpret_cast<uint32_t*>(embt + (size_t)g * 64 + 2 * p) = packed;
}

// ---------------- fused GRU step ----------------
// grid 256 (1 block/CU), block 512 (8 waves, 2x4). Tile: 128 rows x 128 cols,
// 3 gates. Gate-granular phased pipeline: per K-tile 3 phases {ds_read panel,
// issue 1 prefetch item, counted vmcnt(6/6/4), barrier, lgkm0, setprio MFMA},
// A-frags read once per tile and held in regs. vmcnt never 0 in main loop.
// XOR-swizzled LDS (pre-swizzled global src + swizzled ds_read).
__global__ __launch_bounds__(512, 2) void gru_step_kernel(
    const uint16_t* __restrict__ hb_prev,   // [4096][1024] bf16
    float* __restrict__ hf,                 // [4096][1024] f32 (in-place)
    uint16_t* __restrict__ hb_next,         // [4096][1024] bf16
    const uint16_t* __restrict__ recT,      // [3072][1024] bf16
    const uint16_t* __restrict__ kerT,      // [3072][64]   bf16
    const uint16_t* __restrict__ embt,      // [4096][64]   bf16 (this step)
    const float* __restrict__ bias_i,       // [3072]
    const float* __restrict__ bias_r) {     // [3072]
  __shared__ __align__(16) uint16_t sA2[2][128 * 64];      // 32 KB
  __shared__ __align__(16) uint16_t sP[2][3][128 * 64];    // 96 KB

  const int tid  = threadIdx.x;
  const int lane = tid & 63;
  const int wid  = tid >> 6;     // 0..7
  const int wm   = wid >> 2;     // wave row 0..1  (64 rows each)
  const int wn   = wid & 3;      // wave col 0..3  (32 cols each)
  const int bid  = blockIdx.x;
  const int r0   = (bid >> 3) * 128;   // 32 row-blocks
  const int j0   = (bid & 7) * 128;    // 8 col-blocks -> XCD-pinned

  // staged chunk covers row with row&7 == lane>>3 -> swizzled source col:
  const int swz8 = 8 * ((lane & 7) ^ (lane >> 3));

  bf16x8 af[4][2];                      // A-frags, held across a tile's phases
  f32x4 accZ[4][2], accR[4][2], accH[4][2], accX[4][2];
#pragma unroll
  for (int m = 0; m < 4; ++m)
#pragma unroll
    for (int n = 0; n < 2; ++n) {
      accZ[m][n] = (f32x4){0.f, 0.f, 0.f, 0.f};
      accR[m][n] = (f32x4){0.f, 0.f, 0.f, 0.f};
      accH[m][n] = (f32x4){0.f, 0.f, 0.f, 0.f};
      accX[m][n] = (f32x4){0.f, 0.f, 0.f, 0.f};
    }

  // stage A-tile for tile t (2 gld16/thread, 16 KB)
  auto stageA = [&](int t) {
    const int abuf = t & 1;
#pragma unroll
    for (int i = 0; i < 2; ++i) {
      int row = wid * 16 + i * 8 + (lane >> 3);
      const uint16_t* src = (t < 16)
          ? hb_prev + (size_t)(r0 + row) * H_DIM + t * 64 + swz8
          : embt + (size_t)(r0 + row) * 64 + swz8;
      gld16(src, &sA2[abuf][(wid * 128 + i * 64 + lane) * 8]);
    }
  };
  // stage B-panel g of tile t (2 gld16/thread, 16 KB)
  auto stageP = [&](int t, int g) {
    const int pbuf = t & 1;
#pragma unroll
    for (int i = 0; i < 2; ++i) {
      int c = wid * 2 + i;               // col-chunk 0..15
      int n = c * 8 + (lane >> 3);
      const uint16_t* src = (t < 16)
          ? recT + ((size_t)g * H_DIM + j0 + n) * H_DIM + t * 64 + swz8
          : kerT + ((size_t)g * H_DIM + j0 + n) * 64 + swz8;
      gld16(src, &sP[pbuf][g][(c * 64 + lane) * 8]);
    }
  };
  // read A fragments for tile t into af[][] (8 ds_read_b128)
  auto readA = [&](int t) {
    const int abuf = t & 1;
#pragma unroll
    for (int ks = 0; ks < 2; ++ks) {
      const int colswz = (ks * 32 + (lane >> 4) * 8) ^ ((lane & 7) << 3);
#pragma unroll
      for (int mf = 0; mf < 4; ++mf)
        af[mf][ks] = *reinterpret_cast<const bf16x8*>(
            &sA2[abuf][(wm * 64 + mf * 16 + (lane & 15)) * 64 + colswz]);
    }
  };
  // read B fragments of panel g, tile t (4 ds_read_b128)
  auto readB = [&](int t, int g, bf16x8 (&bf)[2][2]) {
    const int pbuf = t & 1;
#pragma unroll
    for (int ks = 0; ks < 2; ++ks) {
      const int colswz = (ks * 32 + (lane >> 4) * 8) ^ ((lane & 7) << 3);
#pragma unroll
      for (int nf = 0; nf < 2; ++nf) {
        int nn = wn * 32 + nf * 16 + (lane & 15);
        bf[nf][ks] = *reinterpret_cast<const bf16x8*>(&sP[pbuf][g][nn * 64 + colswz]);
      }
    }
  };
  // 16 MFMA: af x bf -> acc
  auto MF = [&](bf16x8 (&bf)[2][2], f32x4 (&acc)[4][2]) {
#pragma unroll
    for (int ks = 0; ks < 2; ++ks)
#pragma unroll
      for (int nf = 0; nf < 2; ++nf)
#pragma unroll
        for (int mf = 0; mf < 4; ++mf)
          acc[mf][nf] = __builtin_amdgcn_mfma_f32_16x16x32_bf16(
              af[mf][ks], bf[nf][ks], acc[mf][nf], 0, 0, 0);
  };

  // -------- prologue: tile 0 items in FIFO order [A0, P0z, P0r, P0h] --------
  stageA(0); stageP(0, 0); stageP(0, 1); stageP(0, 2);
  VM_WAIT(4);                 // A0 + P0z landed; P0r, P0h (4 gld) in flight
  BAR();

  // -------- main loop: tiles 0..15, 3 phases each --------
  for (int t = 0; t < 16; ++t) {
    bf16x8 bf[2][2];
    // ---- phase Z ----
    readA(t); readB(t, 0, bf);
    stageA(t + 1); stageP(t + 1, 0);
    VM_WAIT(6);               // P(t,r) landed for next phase
    BAR();
    LGKM0();
    __builtin_amdgcn_s_setprio(1);
    MF(bf, accZ);
    __builtin_amdgcn_s_setprio(0);
    BAR();
    // ---- phase R ----
    readB(t, 1, bf);
    stageP(t + 1, 1);
    VM_WAIT(6);               // P(t,h) landed
    BAR();
    LGKM0();
    __builtin_amdgcn_s_setprio(1);
    MF(bf, accR);
    __builtin_amdgcn_s_setprio(0);
    BAR();
    // ---- phase H ----
    readB(t, 2, bf);
    stageP(t + 1, 2);
    VM_WAIT(4);               // A(t+1) + P(t+1,z) landed for next Z
    BAR();
    LGKM0();
    __builtin_amdgcn_s_setprio(1);
    MF(bf, accH);
    __builtin_amdgcn_s_setprio(0);
    BAR();
  }

  // -------- peeled tile 16 (input projection; h-gate -> accX) --------
  {
    bf16x8 bf[2][2];
    readA(16); readB(16, 0, bf);
    VM_WAIT(2);               // P(16,r) landed
    BAR();
    LGKM0();
    __builtin_amdgcn_s_setprio(1);
    MF(bf, accZ);
    __builtin_amdgcn_s_setprio(0);
    BAR();
    readB(16, 1, bf);
    VM_WAIT(0);               // P(16,h) landed (tail drain ok)
    BAR();
    LGKM0();
    __builtin_amdgcn_s_setprio(1);
    MF(bf, accR);
    __builtin_amdgcn_s_setprio(0);
    BAR();
    readB(16, 2, bf);
    LGKM0();
    __builtin_amdgcn_s_setprio(1);
    MF(bf, accX);
    __builtin_amdgcn_s_setprio(0);
  }

  // -------- epilogue: gates in fp32, write h (f32 master + bf16) --------
#pragma unroll
  for (int nf = 0; nf < 2; ++nf) {
    int col = j0 + wn * 32 + nf * 16 + (lane & 15);
    float b_z = bias_i[col] + bias_r[col];
    float b_r = bias_i[H_DIM + col] + bias_r[H_DIM + col];
    float bih = bias_i[2 * H_DIM + col];
    float brh = bias_r[2 * H_DIM + col];
#pragma unroll
    for (int mf = 0; mf < 4; ++mf) {
#pragma unroll
      for (int q = 0; q < 4; ++q) {
        int row = r0 + wm * 64 + mf * 16 + (lane >> 4) * 4 + q;
        float z  = 1.f / (1.f + __expf(-(accZ[mf][nf][q] + b_z)));
        float rr = 1.f / (1.f + __expf(-(accR[mf][nf][q] + b_r)));
        float pre = accX[mf][nf][q] + bih + rr * (accH[mf][nf][q] + brh);
        float hc  = 2.f / (1.f + __expf(-2.f * pre)) - 1.f;   // tanh
        size_t idx = (size_t)row * H_DIM + col;
        float hold = hf[idx];
        float hnew = z * hold + (1.f - z) * hc;
        hf[idx] = hnew;
        hb_next[idx] = f2bf(hnew);
      }
    }
  }
}

// ---------------- final logits ----------------
__global__ __launch_bounds__(64) void logits_kernel(const float* __restrict__ hf,
                                                    const float* __restrict__ Wd,
                                                    const float* __restrict__ bd,
                                                    float* __restrict__ out) {
  int b = blockIdx.x;
  int l = threadIdx.x;
  float p[NLABEL];
#pragma unroll
  for (int o = 0; o < NLABEL; ++o) p[o] = 0.f;
  for (int kb = 0; kb < 16; ++kb) {
    int k = kb * 64 + l;
    float hv = hf[(size_t)b * H_DIM + k];
#pragma unroll
    for (int o = 0; o < NLABEL; ++o) p[o] += hv * Wd[k * NLABEL + o];
  }
#pragma unroll
  for (int o = 0; o < NLABEL; ++o) {
#pragma unroll
    for (int s = 32; s; s >>= 1) p[o] += __shfl_xor(p[o], s);
  }
  if (l == 0) {
#pragma unroll
    for (int o = 0; o < NLABEL; ++o) out[(size_t)b * NLABEL + o] = p[o] + bd[o];
  }
}

// ---------------- launch ----------------
extern "C" void kernel_launch(void* const* d_in, const int* in_sizes, int n_in,
                              void* d_out, int out_size, void* d_ws, size_t ws_size,
                              hipStream_t stream) {
  const int*   x          = (const int*)d_in[0];
  // d_in[1] = drop_rate (static 0, ignored)
  const float* emb_table  = (const float*)d_in[2];
  const float* kernel_w   = (const float*)d_in[3];
  const float* rec_kernel = (const float*)d_in[4];
  const float* bias_i     = (const float*)d_in[5];
  const float* bias_r     = (const float*)d_in[6];
  const float* Wd         = (const float*)d_in[7];
  const float* bd         = (const float*)d_in[8];
  float* out = (float*)d_out;

  char* ws = (char*)d_ws;
  size_t off = 0;
  auto alloc = [&](size_t bytes) {
    char* p = ws + off;
    off += (bytes + 255) & ~(size_t)255;
    return p;
  };
  float*    hf   = (float*)alloc((size_t)NB * H_DIM * 4);
  uint16_t* hb0  = (uint16_t*)alloc((size_t)NB * H_DIM * 2);
  uint16_t* hb1  = (uint16_t*)alloc((size_t)NB * H_DIM * 2);
  uint16_t* recT = (uint16_t*)alloc((size_t)G3 * H_DIM * 2);
  uint16_t* kerT = (uint16_t*)alloc((size_t)G3 * 64 * 2);
  uint16_t* embt = (uint16_t*)alloc((size_t)TSTEPS * NB * 64 * 2);
  if (off > ws_size) return;  // insufficient workspace -> fail loudly

  hipMemsetAsync(hf, 0, (size_t)NB * H_DIM * 4, stream);
  hipMemsetAsync(hb0, 0, (size_t)NB * H_DIM * 2, stream);

  prep_recT<<<dim3(G3 / 64, H_DIM / 64), 256, 0, stream>>>(rec_kernel, recT);
  prep_kerT<<<G3 / 4, 256, 0, stream>>>(kernel_w, kerT);
  prep_embt<<<TSTEPS * NB * 32 / 256, 256, 0, stream>>>(x, emb_table, embt);

  uint16_t* hb[2] = {hb0, hb1};
  for (int t = 0; t < TSTEPS; ++t) {
    gru_step_kernel<<<256, 512, 0, stream>>>(
        hb[t & 1], hf, hb[(t + 1) & 1], recT, kerT,
        embt + (size_t)t * NB * 64, bias_i, bias_r);
  }
  logits_kernel<<<NB, 64, 0, stream>>>(hf, Wd, bd, out);
}

// Round 5
// 3458.083 us; speedup vs baseline: 2.2106x; 1.0248x over previous
//
#include <hip/hip_runtime.h>
#include <stdint.h>

#define H_DIM   1024
#define G3      3072
#define EMB     50
#define TSTEPS  100
#define NB      4096
#define NLABEL  15

typedef __bf16 bf16x8 __attribute__((ext_vector_type(8)));
typedef float  f32x4  __attribute__((ext_vector_type(4)));

__device__ inline uint16_t f2bf(float f) {
  uint32_t u = __builtin_bit_cast(uint32_t, f);
  u += 0x7FFFu + ((u >> 16) & 1u);   // round-to-nearest-even
  return (uint16_t)(u >> 16);
}

__device__ inline void gld16(const void* g, void* l) {
  __builtin_amdgcn_global_load_lds(
      (const __attribute__((address_space(1))) uint32_t*)g,
      (__attribute__((address_space(3))) uint32_t*)l, 16, 0, 0);
}

#define BARF() do { __builtin_amdgcn_s_barrier(); \
                    asm volatile("" ::: "memory"); } while (0)

// ---------------- prep kernels (buffers stay LINEAR) ----------------

// rec_kernel [1024][3072] f32  ->  recT [3072][1024] bf16 (B^T layout)
__global__ __launch_bounds__(256) void prep_recT(const float* __restrict__ rec,
                                                 uint16_t* __restrict__ recT) {
  __shared__ uint16_t st[64][72];
  const int n0 = blockIdx.x * 64;   // over 3072
  const int k0 = blockIdx.y * 64;   // over 1024
  const int tid = threadIdx.x;
#pragma unroll
  for (int i = 0; i < 16; ++i) {
    int idx = tid + i * 256;
    int r = idx >> 6;    // k offset
    int c = idx & 63;    // n offset
    st[c][r] = f2bf(rec[(size_t)(k0 + r) * G3 + n0 + c]);
  }
  __syncthreads();
#pragma unroll
  for (int i = 0; i < 16; ++i) {
    int idx = tid + i * 256;
    int r = idx >> 6;    // n offset
    int c = idx & 63;    // k offset
    recT[(size_t)(n0 + r) * H_DIM + k0 + c] = st[r][c];
  }
}

// kernel [50][3072] f32 -> kerT [3072][64] bf16, zero-padded k in [50,64)
__global__ __launch_bounds__(256) void prep_kerT(const float* __restrict__ ker,
                                                 uint16_t* __restrict__ kerT) {
  int n = blockIdx.x * 4 + (threadIdx.x >> 6);   // 0..3071
  int k = threadIdx.x & 63;
  float v = (k < EMB) ? ker[(size_t)k * G3 + n] : 0.f;
  kerT[(size_t)n * 64 + k] = f2bf(v);
}

// embt [100][4096][64] bf16 = emb_table[x[b,t]], zero-padded cols [50,64)
__global__ __launch_bounds__(256) void prep_embt(const int* __restrict__ x,
                                                 const float* __restrict__ tab,
                                                 uint16_t* __restrict__ embt) {
  int idx = blockIdx.x * 256 + threadIdx.x;   // pair index
  int g = idx >> 5;          // row: t*4096 + b
  int p = idx & 31;          // pair 0..31 -> cols 2p, 2p+1
  int t = g >> 12;
  int b = g & 4095;
  int row = x[b * TSTEPS + t];
  float2 v;
  if (p < 25) v = *reinterpret_cast<const float2*>(tab + (size_t)row * EMB + 2 * p);
  else { v.x = 0.f; v.y = 0.f; }
  uint32_t packed = (uint32_t)f2bf(v.x) | ((uint32_t)f2bf(v.y) << 16);
  *reinterpret_cast<uint32_t*>(embt + (size_t)g * 64 + 2 * p) = packed;
}

// ---------------- fused GRU step ----------------
// grid 256 (1 block/CU), block 512 (8 waves, 2x4). Tile: 128 rows x 128 cols,
// 3 gates. One barrier per phase; B-frags double-buffered in regs (read one
// phase ahead, lgkm never drains); counted vmcnt (FIFO-derived 6/4/6, never 0
// until the peeled tail). XCD remap: each XCD = 8 row-blocks x 4 col-blocks.
__global__ __launch_bounds__(512, 2) void gru_step_kernel(
    const uint16_t* __restrict__ hb_prev,   // [4096][1024] bf16
    float* __restrict__ hf,                 // [4096][1024] f32 (in-place)
    uint16_t* __restrict__ hb_next,         // [4096][1024] bf16
    const uint16_t* __restrict__ recT,      // [3072][1024] bf16
    const uint16_t* __restrict__ kerT,      // [3072][64]   bf16
    const uint16_t* __restrict__ embt,      // [4096][64]   bf16 (this step)
    const float* __restrict__ bias_i,       // [3072]
    const float* __restrict__ bias_r) {     // [3072]
  __shared__ __align__(16) uint16_t sA2[2][128 * 64];      // 32 KB
  __shared__ __align__(16) uint16_t sP[2][3][128 * 64];    // 96 KB

  const int tid  = threadIdx.x;
  const int lane = tid & 63;
  const int wid  = tid >> 6;     // 0..7
  const int wm   = wid >> 2;     // wave row 0..1  (64 rows each)
  const int wn   = wid & 3;      // wave col 0..3  (32 cols each)
  const int bid  = blockIdx.x;
  // XCD remap: k = bid%8 -> (rg,cg); each XCD: 8 row-blocks x 4 col-blocks
  const int xk = bid & 7, slot = bid >> 3;
  const int rowblk = (xk >> 1) * 8 + (slot >> 2);   // 0..31
  const int colblk = (xk & 1) * 4 + (slot & 3);     // 0..7
  const int r0 = rowblk * 128;
  const int j0 = colblk * 128;

  // staged chunk covers row with row&7 == lane>>3 -> swizzled source col:
  const int swz8 = 8 * ((lane & 7) ^ (lane >> 3));

  bf16x8 af[4][2];         // A-frags (single-buffered)
  bf16x8 bf0[2][2], bf1[2][2];   // B-frag double buffer
  f32x4 accZ[4][2], accR[4][2], accH[4][2], accX[4][2];
#pragma unroll
  for (int m = 0; m < 4; ++m)
#pragma unroll
    for (int n = 0; n < 2; ++n) {
      accZ[m][n] = (f32x4){0.f, 0.f, 0.f, 0.f};
      accR[m][n] = (f32x4){0.f, 0.f, 0.f, 0.f};
      accH[m][n] = (f32x4){0.f, 0.f, 0.f, 0.f};
      accX[m][n] = (f32x4){0.f, 0.f, 0.f, 0.f};
    }

  // stage A-tile for tile t (2 gld16/thread, 16 KB)
  auto stageA = [&](int t) {
    const int abuf = t & 1;
#pragma unroll
    for (int i = 0; i < 2; ++i) {
      int row = wid * 16 + i * 8 + (lane >> 3);
      const uint16_t* src = (t < 16)
          ? hb_prev + (size_t)(r0 + row) * H_DIM + t * 64 + swz8
          : embt + (size_t)(r0 + row) * 64 + swz8;
      gld16(src, &sA2[abuf][(wid * 128 + i * 64 + lane) * 8]);
    }
  };
  // stage B-panel g of tile t (2 gld16/thread, 16 KB)
  auto stageP = [&](int t, int g) {
    const int pbuf = t & 1;
#pragma unroll
    for (int i = 0; i < 2; ++i) {
      int c = wid * 2 + i;               // col-chunk 0..15
      int n = c * 8 + (lane >> 3);
      const uint16_t* src = (t < 16)
          ? recT + ((size_t)g * H_DIM + j0 + n) * H_DIM + t * 64 + swz8
          : kerT + ((size_t)g * H_DIM + j0 + n) * 64 + swz8;
      gld16(src, &sP[pbuf][g][(c * 64 + lane) * 8]);
    }
  };
  // read A fragments for tile t into af[][] (8 ds_read_b128)
  auto readA = [&](int t) {
    const int abuf = t & 1;
#pragma unroll
    for (int ks = 0; ks < 2; ++ks) {
      const int colswz = (ks * 32 + (lane >> 4) * 8) ^ ((lane & 7) << 3);
#pragma unroll
      for (int mf = 0; mf < 4; ++mf)
        af[mf][ks] = *reinterpret_cast<const bf16x8*>(
            &sA2[abuf][(wm * 64 + mf * 16 + (lane & 15)) * 64 + colswz]);
    }
  };
  // read B fragments of panel g, tile t (4 ds_read_b128)
  auto readB = [&](int t, int g, bf16x8 (&bf)[2][2]) {
    const int pbuf = t & 1;
#pragma unroll
    for (int ks = 0; ks < 2; ++ks) {
      const int colswz = (ks * 32 + (lane >> 4) * 8) ^ ((lane & 7) << 3);
#pragma unroll
      for (int nf = 0; nf < 2; ++nf) {
        int nn = wn * 32 + nf * 16 + (lane & 15);
        bf[nf][ks] = *reinterpret_cast<const bf16x8*>(&sP[pbuf][g][nn * 64 + colswz]);
      }
    }
  };
  // 16 MFMA: af x bf -> acc
  auto MF = [&](bf16x8 (&bf)[2][2], f32x4 (&acc)[4][2]) {
    __builtin_amdgcn_s_setprio(1);
#pragma unroll
    for (int ks = 0; ks < 2; ++ks)
#pragma unroll
      for (int nf = 0; nf < 2; ++nf)
#pragma unroll
        for (int mf = 0; mf < 4; ++mf)
          acc[mf][nf] = __builtin_amdgcn_mfma_f32_16x16x32_bf16(
              af[mf][ks], bf[nf][ks], acc[mf][nf], 0, 0, 0);
    __builtin_amdgcn_s_setprio(0);
  };

// phase: ds_read(next) -> MFMA(cur) -> stage -> counted vmcnt -> barrier
#define PH(DSRD, MFBUF, MFACC, STG, WN) do { \
    DSRD; MF(MFBUF, MFACC); STG; \
    asm volatile("s_waitcnt vmcnt(" #WN ")" ::: "memory"); \
    BARF(); \
  } while (0)
// H-phase variant: MFMA first (readA(t+1) would overwrite af used by MFMA)
#define PHH(MFBUF, MFACC, DSRD, STG, WN) do { \
    MF(MFBUF, MFACC); DSRD; STG; \
    asm volatile("s_waitcnt vmcnt(" #WN ")" ::: "memory"); \
    BARF(); \
  } while (0)
// steady tile: Z{readB(t,1)->BFB | MFMA BFA->accZ | stage P1(t+1) | w6}
//              R{readB(t,2)->BFA | MFMA BFB->accR | stage P2(t+1) | w4}
//              H{MFMA BFA->accH | readA(t+1),readB(t+1,0)->BFB | stage A,P0(t+2) | w6}
#define TILE_STEADY(t, BFA, BFB) do { \
    PH(readB(t, 1, BFB), BFA, accZ, stageP((t) + 1, 1), 6); \
    PH(readB(t, 2, BFA), BFB, accR, stageP((t) + 1, 2), 4); \
    PHH(BFA, accH, (readA((t) + 1), readB((t) + 1, 0, BFB)), \
        (stageA((t) + 2), stageP((t) + 2, 0)), 6); \
  } while (0)

  // -------- prologue: tile 0 fully + A(1),P0(1); drain; pre-read frags ------
  stageA(0); stageP(0, 0); stageP(0, 1); stageP(0, 2);
  stageA(1); stageP(1, 0);
  asm volatile("s_waitcnt vmcnt(0)" ::: "memory");
  BARF();
  readA(0); readB(0, 0, bf0);

  // -------- main loop: tiles 0..13 (2-tile unroll for bf parity), then 14 ---
  for (int tt = 0; tt < 14; tt += 2) {
    TILE_STEADY(tt, bf0, bf1);
    TILE_STEADY(tt + 1, bf1, bf0);
  }
  TILE_STEADY(14, bf0, bf1);
  // tile 15 (odd): Z,R steady; H has no stage -> tail-exact wait 2
  PH(readB(15, 1, bf0), bf1, accZ, stageP(16, 1), 6);
  PH(readB(15, 2, bf1), bf0, accR, stageP(16, 2), 4);
  PHH(bf1, accH, (readA(16), readB(16, 0, bf0)), (void)0, 2);
  // tile 16 (even, input projection; h-gate -> accX)
  PH(readB(16, 1, bf1), bf0, accZ, (void)0, 0);
  PH(readB(16, 2, bf0), bf1, accR, (void)0, 0);
  MF(bf0, accX);                 // last cluster; no barrier needed

  // -------- epilogue: gates in fp32, write h (f32 master + bf16) --------
#pragma unroll
  for (int nf = 0; nf < 2; ++nf) {
    int col = j0 + wn * 32 + nf * 16 + (lane & 15);
    float b_z = bias_i[col] + bias_r[col];
    float b_r = bias_i[H_DIM + col] + bias_r[H_DIM + col];
    float bih = bias_i[2 * H_DIM + col];
    float brh = bias_r[2 * H_DIM + col];
#pragma unroll
    for (int mf = 0; mf < 4; ++mf) {
#pragma unroll
      for (int q = 0; q < 4; ++q) {
        int row = r0 + wm * 64 + mf * 16 + (lane >> 4) * 4 + q;
        float z  = 1.f / (1.f + __expf(-(accZ[mf][nf][q] + b_z)));
        float rr = 1.f / (1.f + __expf(-(accR[mf][nf][q] + b_r)));
        float pre = accX[mf][nf][q] + bih + rr * (accH[mf][nf][q] + brh);
        float hc  = 2.f / (1.f + __expf(-2.f * pre)) - 1.f;   // tanh
        size_t idx = (size_t)row * H_DIM + col;
        float hold = hf[idx];
        float hnew = z * hold + (1.f - z) * hc;
        hf[idx] = hnew;
        hb_next[idx] = f2bf(hnew);
      }
    }
  }
#undef PH
#undef PHH
#undef TILE_STEADY
}

// ---------------- final logits ----------------
__global__ __launch_bounds__(64) void logits_kernel(const float* __restrict__ hf,
                                                    const float* __restrict__ Wd,
                                                    const float* __restrict__ bd,
                                                    float* __restrict__ out) {
  int b = blockIdx.x;
  int l = threadIdx.x;
  float p[NLABEL];
#pragma unroll
  for (int o = 0; o < NLABEL; ++o) p[o] = 0.f;
  for (int kb = 0; kb < 16; ++kb) {
    int k = kb * 64 + l;
    float hv = hf[(size_t)b * H_DIM + k];
#pragma unroll
    for (int o = 0; o < NLABEL; ++o) p[o] += hv * Wd[k * NLABEL + o];
  }
#pragma unroll
  for (int o = 0; o < NLABEL; ++o) {
#pragma unroll
    for (int s = 32; s; s >>= 1) p[o] += __shfl_xor(p[o], s);
  }
  if (l == 0) {
#pragma unroll
    for (int o = 0; o < NLABEL; ++o) out[(size_t)b * NLABEL + o] = p[o] + bd[o];
  }
}

// ---------------- launch ----------------
extern "C" void kernel_launch(void* const* d_in, const int* in_sizes, int n_in,
                              void* d_out, int out_size, void* d_ws, size_t ws_size,
                              hipStream_t stream) {
  const int*   x          = (const int*)d_in[0];
  // d_in[1] = drop_rate (static 0, ignored)
  const float* emb_table  = (const float*)d_in[2];
  const float* kernel_w   = (const float*)d_in[3];
  const float* rec_kernel = (const float*)d_in[4];
  const float* bias_i     = (const float*)d_in[5];
  const float* bias_r     = (const float*)d_in[6];
  const float* Wd         = (const float*)d_in[7];
  const float* bd         = (const float*)d_in[8];
  float* out = (float*)d_out;

  char* ws = (char*)d_ws;
  size_t off = 0;
  auto alloc = [&](size_t bytes) {
    char* p = ws + off;
    off += (bytes + 255) & ~(size_t)255;
    return p;
  };
  float*    hf   = (float*)alloc((size_t)NB * H_DIM * 4);
  uint16_t* hb0  = (uint16_t*)alloc((size_t)NB * H_DIM * 2);
  uint16_t* hb1  = (uint16_t*)alloc((size_t)NB * H_DIM * 2);
  uint16_t* recT = (uint16_t*)alloc((size_t)G3 * H_DIM * 2);
  uint16_t* kerT = (uint16_t*)alloc((size_t)G3 * 64 * 2);
  uint16_t* embt = (uint16_t*)alloc((size_t)TSTEPS * NB * 64 * 2);
  if (off > ws_size) return;  // insufficient workspace -> fail loudly

  hipMemsetAsync(hf, 0, (size_t)NB * H_DIM * 4, stream);
  hipMemsetAsync(hb0, 0, (size_t)NB * H_DIM * 2, stream);

  prep_recT<<<dim3(G3 / 64, H_DIM / 64), 256, 0, stream>>>(rec_kernel, recT);
  prep_kerT<<<G3 / 4, 256, 0, stream>>>(kernel_w, kerT);
  prep_embt<<<TSTEPS * NB * 32 / 256, 256, 0, stream>>>(x, emb_table, embt);

  uint16_t* hb[2] = {hb0, hb1};
  for (int t = 0; t < TSTEPS; ++t) {
    gru_step_kernel<<<256, 512, 0, stream>>>(
        hb[t & 1], hf, hb[(t + 1) & 1], recT, kerT,
        embt + (size_t)t * NB * 64, bias_i, bias_r);
  }
  logits_kernel<<<NB, 64, 0, stream>>>(hf, Wd, bd, out);
}